// Round 1
// baseline (946.826 us; speedup 1.0000x reference)
//
#include <hip/hip_runtime.h>
#include <hip/hip_bf16.h>
#include <cstdint>
#include <cstddef>

#define M_DIM 16384
#define K_DIM 4096
#define N_DIM 4096

typedef __attribute__((ext_vector_type(8))) short bf16x8;
typedef __attribute__((ext_vector_type(4))) float f32x4;

static __device__ __forceinline__ unsigned short f2bf(float f) {
    // round-to-nearest-even fp32 -> bf16 (inputs finite; no NaN path needed)
    union { float f; unsigned int u; } v;
    v.f = f;
    unsigned int lsb = (v.u >> 16) & 1u;
    v.u += 0x7fffu + lsb;
    return (unsigned short)(v.u >> 16);
}

// ---------------------------------------------------------------------------
// Kernel 1: x (M x K fp32) -> xb (M x K bf16), fully vectorized (16B in/out)
// ---------------------------------------------------------------------------
__global__ __launch_bounds__(256) void cvt_x_kernel(const float* __restrict__ x,
                                                    unsigned short* __restrict__ xb) {
    long i = (long)blockIdx.x * blockDim.x + threadIdx.x;  // one 8-float group per thread
    const float4* px = reinterpret_cast<const float4*>(x);
    float4 a = px[2 * i];
    float4 b = px[2 * i + 1];
    bf16x8 r;
    r[0] = (short)f2bf(a.x); r[1] = (short)f2bf(a.y);
    r[2] = (short)f2bf(a.z); r[3] = (short)f2bf(a.w);
    r[4] = (short)f2bf(b.x); r[5] = (short)f2bf(b.y);
    r[6] = (short)f2bf(b.z); r[7] = (short)f2bf(b.w);
    *reinterpret_cast<bf16x8*>(xb + i * 8) = r;
}

// ---------------------------------------------------------------------------
// Kernel 2: W (K x N fp32, row-major) -> WT (N x K bf16, row-major) transpose
// 64x64 fp32 LDS tile, +1 pad, coalesced read along N and write along K.
// ---------------------------------------------------------------------------
__global__ __launch_bounds__(256) void cvt_wt_kernel(const float* __restrict__ W,
                                                     unsigned short* __restrict__ WT) {
    __shared__ float tile[64][65];
    int k0 = blockIdx.x * 64;
    int n0 = blockIdx.y * 64;
    int t = threadIdx.x;

    int c4 = (t & 15) * 4;   // col within tile (N dim), float4
    int r  = t >> 4;         // 16 rows per pass
#pragma unroll
    for (int p = 0; p < 4; ++p) {
        int kk = r + p * 16;
        float4 v = *reinterpret_cast<const float4*>(&W[(size_t)(k0 + kk) * N_DIM + n0 + c4]);
        tile[kk][c4 + 0] = v.x;
        tile[kk][c4 + 1] = v.y;
        tile[kk][c4 + 2] = v.z;
        tile[kk][c4 + 3] = v.w;
    }
    __syncthreads();

    int ck = (t & 7) * 8;    // col within tile (K dim), 8 bf16 out
    int rn = t >> 3;         // 32 rows (N) per pass
#pragma unroll
    for (int p = 0; p < 2; ++p) {
        int nn = rn + p * 32;
        bf16x8 o;
#pragma unroll
        for (int j = 0; j < 8; ++j) o[j] = (short)f2bf(tile[ck + j][nn]);
        *reinterpret_cast<bf16x8*>(&WT[(size_t)(n0 + nn) * K_DIM + k0 + ck]) = o;
    }
}

// ---------------------------------------------------------------------------
// GEMM: C (M x N fp32) = A (M x K) * B (K x N) + bias, bf16 MFMA 16x16x32.
// m97 structure: BM=BN=128, BK=64, 256 threads = 4 waves (2x2), 64x64/wave,
// 4x4 fragments, single-buffered LDS, global_load_lds width-16 staging.
// PRECONV=true: A/B already bf16 (B transposed to NxK) in workspace.
// PRECONV=false: fallback, reg-staged fp32->bf16 conversion in the GEMM.
// ---------------------------------------------------------------------------
template <bool PRECONV>
__global__ __launch_bounds__(256) void gemm_kernel(const void* __restrict__ Ap,
                                                   const void* __restrict__ Bp,
                                                   const float* __restrict__ bias,
                                                   float* __restrict__ C) {
    __shared__ unsigned short As[128 * 64];
    __shared__ unsigned short Bs[128 * 64];

    // XCD-aware swizzle: 4096 blocks % 8 == 0 -> simple bijective swizzle valid
    int bid = blockIdx.x;
    int swz = (bid & 7) * (4096 / 8) + (bid >> 3);
    int nt = swz & 31;   // 32 n-tiles
    int mt = swz >> 5;   // 128 m-tiles
    int m0 = mt * 128;
    int n0 = nt * 128;

    int t = threadIdx.x;
    int l = t & 63;
    int wid = t >> 6;
    int wr = wid >> 1;   // wave row (2)
    int wc = wid & 1;    // wave col (2)
    int lr = l & 15;     // fragment row/col lane index
    int lg = l >> 4;     // lane group (K chunk / C row group)

    f32x4 acc[4][4];
#pragma unroll
    for (int m = 0; m < 4; ++m)
#pragma unroll
        for (int n = 0; n < 4; ++n) acc[m][n] = (f32x4)(0.0f);

    for (int kt = 0; kt < K_DIM; kt += 64) {
        if constexpr (PRECONV) {
            const unsigned short* A  = (const unsigned short*)Ap;  // M x K bf16
            const unsigned short* Bt = (const unsigned short*)Bp;  // N x K bf16
#pragma unroll
            for (int i = 0; i < 4; ++i) {
                int off = (i * 256 + t) * 8;          // flat element in 128x64 tile
                int row = off >> 6;
                int col = off & 63;
                const unsigned short* ga = A  + (size_t)(m0 + row) * K_DIM + kt + col;
                const unsigned short* gb = Bt + (size_t)(n0 + row) * K_DIM + kt + col;
                __builtin_amdgcn_global_load_lds(
                    (const __attribute__((address_space(1))) unsigned int*)ga,
                    (__attribute__((address_space(3))) unsigned int*)&As[off], 16, 0, 0);
                __builtin_amdgcn_global_load_lds(
                    (const __attribute__((address_space(1))) unsigned int*)gb,
                    (__attribute__((address_space(3))) unsigned int*)&Bs[off], 16, 0, 0);
            }
        } else {
            const float* Af = (const float*)Ap;  // M x K fp32
            const float* Wf = (const float*)Bp;  // K x N fp32
#pragma unroll
            for (int i = 0; i < 4; ++i) {
                int off = (i * 256 + t) * 8;
                int row = off >> 6;
                int col = off & 63;
                const float4* pa =
                    reinterpret_cast<const float4*>(&Af[(size_t)(m0 + row) * K_DIM + kt + col]);
                float4 a = pa[0], b = pa[1];
                bf16x8 r;
                r[0] = (short)f2bf(a.x); r[1] = (short)f2bf(a.y);
                r[2] = (short)f2bf(a.z); r[3] = (short)f2bf(a.w);
                r[4] = (short)f2bf(b.x); r[5] = (short)f2bf(b.y);
                r[6] = (short)f2bf(b.z); r[7] = (short)f2bf(b.w);
                *reinterpret_cast<bf16x8*>(&As[off]) = r;
            }
            // B tile with in-stage transpose: read W[k][n] coalesced, scatter Bs[n][k]
#pragma unroll
            for (int i = 0; i < 4; ++i) {
                int off = (i * 256 + t) * 8;          // flat over [k in 64][n in 128]
                int k = off >> 7;
                int n = off & 127;
                const float4* pw =
                    reinterpret_cast<const float4*>(&Wf[(size_t)(kt + k) * N_DIM + n0 + n]);
                float4 a = pw[0], b = pw[1];
                float v[8] = {a.x, a.y, a.z, a.w, b.x, b.y, b.z, b.w};
#pragma unroll
                for (int j = 0; j < 8; ++j) Bs[(n + j) * 64 + k] = f2bf(v[j]);
            }
        }
        __syncthreads();

#pragma unroll
        for (int ks = 0; ks < 2; ++ks) {
            bf16x8 af[4], bfr[4];
#pragma unroll
            for (int m = 0; m < 4; ++m)
                af[m] = *reinterpret_cast<const bf16x8*>(
                    &As[(wr * 64 + m * 16 + lr) * 64 + ks * 32 + lg * 8]);
#pragma unroll
            for (int n = 0; n < 4; ++n)
                bfr[n] = *reinterpret_cast<const bf16x8*>(
                    &Bs[(wc * 64 + n * 16 + lr) * 64 + ks * 32 + lg * 8]);
#pragma unroll
            for (int m = 0; m < 4; ++m)
#pragma unroll
                for (int n = 0; n < 4; ++n)
                    acc[m][n] = __builtin_amdgcn_mfma_f32_16x16x32_bf16(af[m], bfr[n],
                                                                        acc[m][n], 0, 0, 0);
        }
        __syncthreads();
    }

    // Epilogue: C/D layout col = lane&15, row = (lane>>4)*4 + reg (m89/m91-verified)
#pragma unroll
    for (int n = 0; n < 4; ++n) {
        int col = n0 + wc * 64 + n * 16 + lr;
        float bv = bias[col];
#pragma unroll
        for (int m = 0; m < 4; ++m) {
#pragma unroll
            for (int j = 0; j < 4; ++j) {
                int row = m0 + wr * 64 + m * 16 + lg * 4 + j;
                C[(size_t)row * N_DIM + col] = acc[m][n][j] + bv;
            }
        }
    }
}

// ---------------------------------------------------------------------------
extern "C" void kernel_launch(void* const* d_in, const int* in_sizes, int n_in,
                              void* d_out, int out_size, void* d_ws, size_t ws_size,
                              hipStream_t stream) {
    const float* x    = (const float*)d_in[0];   // (8,2048,4096) fp32
    const float* w    = (const float*)d_in[1];   // (4096,4096) fp32 ternary
    const float* bias = (const float*)d_in[2];   // (4096,) fp32
    float* out = (float*)d_out;

    const size_t needA = (size_t)M_DIM * K_DIM * sizeof(unsigned short); // 128 MB
    const size_t needB = (size_t)N_DIM * K_DIM * sizeof(unsigned short); //  32 MB

    if (ws_size >= needA + needB) {
        unsigned short* xb = (unsigned short*)d_ws;
        unsigned short* wt = (unsigned short*)((char*)d_ws + needA);

        // x fp32 -> bf16 (one 8-elem group per thread; exact coverage)
        long groups = (long)M_DIM * K_DIM / 8;  // 8,388,608
        cvt_x_kernel<<<(unsigned)(groups / 256), 256, 0, stream>>>(x, xb);

        // W fp32 (KxN) -> bf16 W^T (NxK)
        cvt_wt_kernel<<<dim3(K_DIM / 64, N_DIM / 64), 256, 0, stream>>>(w, wt);

        gemm_kernel<true><<<(M_DIM / 128) * (N_DIM / 128), 256, 0, stream>>>(xb, wt, bias, out);
    } else {
        // Fallback: convert inside the GEMM (reg-staged), no workspace needed
        gemm_kernel<false><<<(M_DIM / 128) * (N_DIM / 128), 256, 0, stream>>>(x, w, bias, out);
    }
}

// Round 2
// 847.781 us; speedup vs baseline: 1.1168x; 1.1168x over previous
//
#include <hip/hip_runtime.h>
#include <hip/hip_bf16.h>
#include <cstdint>
#include <cstddef>

#define M_DIM 16384
#define K_DIM 4096
#define N_DIM 4096

// A/B workspace layout: tiled + swizzled.
// tile = 128 rows x 64 k (bf16) = 1024 chunks of 16B (8 bf16).
// chunk (r, c_store) of a tile holds logical k-chunk c_data = c_store ^ (r&7) of row r.
// A tiles ordered [mt][kt] (mt 0..127, kt 0..63); B tiles [nt][kt] (nt 0..31).

typedef __attribute__((ext_vector_type(8))) short bf16x8;
typedef __attribute__((ext_vector_type(4))) float f32x4;

static __device__ __forceinline__ unsigned short f2bf(float f) {
    union { float f; unsigned int u; } v;
    v.f = f;
    unsigned int lsb = (v.u >> 16) & 1u;
    v.u += 0x7fffu + lsb;
    return (unsigned short)(v.u >> 16);
}

// ---------------------------------------------------------------------------
// Kernel 1: x (M x K fp32) -> xb tiled+swizzled bf16. One 16B chunk per thread.
// ---------------------------------------------------------------------------
__global__ __launch_bounds__(256) void cvt_x_tile_kernel(const float* __restrict__ x,
                                                         unsigned short* __restrict__ xb) {
    long F = (long)blockIdx.x * 256 + threadIdx.x;   // chunk id
    long tile = F >> 10;                              // 1024 chunks per tile
    int within = (int)(F & 1023);
    int r = within >> 3;
    int c_store = within & 7;
    int mt = (int)(tile >> 6);                        // 64 k-tiles per m-tile
    int kt = (int)(tile & 63);
    int c_data = c_store ^ (r & 7);
    size_t row = (size_t)mt * 128 + r;
    size_t col = (size_t)kt * 64 + c_data * 8;
    const float4* ps = reinterpret_cast<const float4*>(&x[row * K_DIM + col]);
    float4 a = ps[0], b = ps[1];
    bf16x8 o;
    o[0] = (short)f2bf(a.x); o[1] = (short)f2bf(a.y);
    o[2] = (short)f2bf(a.z); o[3] = (short)f2bf(a.w);
    o[4] = (short)f2bf(b.x); o[5] = (short)f2bf(b.y);
    o[6] = (short)f2bf(b.z); o[7] = (short)f2bf(b.w);
    *reinterpret_cast<bf16x8*>(&xb[F * 8]) = o;
}

// ---------------------------------------------------------------------------
// Kernel 2: W (K x N fp32) -> W^T tiled+swizzled bf16 (N-major tiles).
// 64x64 LDS transpose, +1 pad; output chunks land in swizzled tile slots.
// ---------------------------------------------------------------------------
__global__ __launch_bounds__(256) void cvt_wt_tile_kernel(const float* __restrict__ W,
                                                          unsigned short* __restrict__ WT) {
    __shared__ float tile[64][65];
    int k0 = blockIdx.x * 64;
    int n0 = blockIdx.y * 64;
    int t = threadIdx.x;

    int c4 = (t & 15) * 4;
    int rr = t >> 4;
#pragma unroll
    for (int p = 0; p < 4; ++p) {
        int kk = rr + p * 16;
        float4 v = *reinterpret_cast<const float4*>(&W[(size_t)(k0 + kk) * N_DIM + n0 + c4]);
        tile[kk][c4 + 0] = v.x;
        tile[kk][c4 + 1] = v.y;
        tile[kk][c4 + 2] = v.z;
        tile[kk][c4 + 3] = v.w;
    }
    __syncthreads();

    int c_data = t & 7;          // k-chunk within this kt
    int ck = c_data * 8;         // k element offset in tile
    int rn = t >> 3;
    int kt = blockIdx.x;         // k0 / 64
#pragma unroll
    for (int p = 0; p < 2; ++p) {
        int nn = rn + p * 32;
        int n_g = n0 + nn;
        int nt = n_g >> 7;
        int r = n_g & 127;
        int c_store = c_data ^ (r & 7);
        bf16x8 o;
#pragma unroll
        for (int j = 0; j < 8; ++j) o[j] = (short)f2bf(tile[ck + j][nn]);
        size_t dst = (((size_t)nt * 64 + kt) << 13) + r * 64 + c_store * 8;
        *reinterpret_cast<bf16x8*>(&WT[dst]) = o;
    }
}

// ---------------------------------------------------------------------------
// GEMM: C = A*B + bias, bf16 MFMA 16x16x32. BM=BN=128, BK=64, 4 waves (2x2).
// PRECONV: workspace tiles are pre-swizzled; staging is linear global_load_lds;
// fragment ds_read applies the XOR swizzle -> bank-conflict-free.
// ---------------------------------------------------------------------------
template <bool PRECONV>
__global__ __launch_bounds__(256) void gemm_kernel(const void* __restrict__ Ap,
                                                   const void* __restrict__ Bp,
                                                   const float* __restrict__ bias,
                                                   float* __restrict__ C) {
    __shared__ unsigned short As[128 * 64];
    __shared__ unsigned short Bs[128 * 64];

    int bid = blockIdx.x;
    int swz = (bid & 7) * (4096 / 8) + (bid >> 3);   // grid 4096, %8==0 -> bijective
    int nt = swz & 31;
    int mt = swz >> 5;
    int m0 = mt * 128;
    int n0 = nt * 128;

    int t = threadIdx.x;
    int l = t & 63;
    int wid = t >> 6;
    int wr = wid >> 1;
    int wc = wid & 1;
    int lr = l & 15;
    int lg = l >> 4;

    f32x4 acc[4][4];
#pragma unroll
    for (int m = 0; m < 4; ++m)
#pragma unroll
        for (int n = 0; n < 4; ++n) acc[m][n] = (f32x4)(0.0f);

    for (int kt = 0; kt < 64; ++kt) {
        if constexpr (PRECONV) {
            const unsigned short* A  = (const unsigned short*)Ap;
            const unsigned short* Bt = (const unsigned short*)Bp;
            const unsigned short* Atile = A  + (((size_t)mt * 64 + kt) << 13);
            const unsigned short* Btile = Bt + (((size_t)nt * 64 + kt) << 13);
#pragma unroll
            for (int i = 0; i < 4; ++i) {
                int off = i * 256 + t;
                __builtin_amdgcn_global_load_lds(
                    (const __attribute__((address_space(1))) unsigned int*)(Atile + (size_t)off * 8),
                    (__attribute__((address_space(3))) unsigned int*)&As[off * 8], 16, 0, 0);
                __builtin_amdgcn_global_load_lds(
                    (const __attribute__((address_space(1))) unsigned int*)(Btile + (size_t)off * 8),
                    (__attribute__((address_space(3))) unsigned int*)&Bs[off * 8], 16, 0, 0);
            }
        } else {
            const float* Af = (const float*)Ap;
            const float* Wf = (const float*)Bp;
#pragma unroll
            for (int i = 0; i < 4; ++i) {
                int off = (i * 256 + t) * 8;
                int row = off >> 6;
                int col = off & 63;
                const float4* pa =
                    reinterpret_cast<const float4*>(&Af[(size_t)(m0 + row) * K_DIM + kt * 64 + col]);
                float4 a = pa[0], b = pa[1];
                bf16x8 rg;
                rg[0] = (short)f2bf(a.x); rg[1] = (short)f2bf(a.y);
                rg[2] = (short)f2bf(a.z); rg[3] = (short)f2bf(a.w);
                rg[4] = (short)f2bf(b.x); rg[5] = (short)f2bf(b.y);
                rg[6] = (short)f2bf(b.z); rg[7] = (short)f2bf(b.w);
                *reinterpret_cast<bf16x8*>(&As[off]) = rg;
            }
#pragma unroll
            for (int i = 0; i < 4; ++i) {
                int off = (i * 256 + t) * 8;
                int k = off >> 7;
                int n = off & 127;
                const float4* pw =
                    reinterpret_cast<const float4*>(&Wf[(size_t)(kt * 64 + k) * N_DIM + n0 + n]);
                float4 a = pw[0], b = pw[1];
                float v[8] = {a.x, a.y, a.z, a.w, b.x, b.y, b.z, b.w};
#pragma unroll
                for (int j = 0; j < 8; ++j) Bs[(n + j) * 64 + k] = f2bf(v[j]);
            }
        }
        __syncthreads();

#pragma unroll
        for (int ks = 0; ks < 2; ++ks) {
            bf16x8 af[4], bfr[4];
            int c = (ks << 2) | lg;
            int ca = PRECONV ? (c ^ (lr & 7)) : c;   // swizzled read iff preconv layout
#pragma unroll
            for (int m = 0; m < 4; ++m) {
                int row = wr * 64 + m * 16 + lr;
                af[m] = *reinterpret_cast<const bf16x8*>(&As[row * 64 + ca * 8]);
            }
#pragma unroll
            for (int n = 0; n < 4; ++n) {
                int row = wc * 64 + n * 16 + lr;
                bfr[n] = *reinterpret_cast<const bf16x8*>(&Bs[row * 64 + ca * 8]);
            }
#pragma unroll
            for (int m = 0; m < 4; ++m)
#pragma unroll
                for (int n = 0; n < 4; ++n)
                    acc[m][n] = __builtin_amdgcn_mfma_f32_16x16x32_bf16(af[m], bfr[n],
                                                                        acc[m][n], 0, 0, 0);
        }
        __syncthreads();
    }

    // C/D layout: col = lane&15, row = (lane>>4)*4 + reg (m89/m91-verified)
#pragma unroll
    for (int n = 0; n < 4; ++n) {
        int col = n0 + wc * 64 + n * 16 + lr;
        float bv = bias[col];
#pragma unroll
        for (int m = 0; m < 4; ++m) {
#pragma unroll
            for (int j = 0; j < 4; ++j) {
                int row = m0 + wr * 64 + m * 16 + lg * 4 + j;
                C[(size_t)row * N_DIM + col] = acc[m][n][j] + bv;
            }
        }
    }
}

// ---------------------------------------------------------------------------
extern "C" void kernel_launch(void* const* d_in, const int* in_sizes, int n_in,
                              void* d_out, int out_size, void* d_ws, size_t ws_size,
                              hipStream_t stream) {
    const float* x    = (const float*)d_in[0];
    const float* w    = (const float*)d_in[1];
    const float* bias = (const float*)d_in[2];
    float* out = (float*)d_out;

    const size_t needA = (size_t)M_DIM * K_DIM * sizeof(unsigned short); // 128 MB
    const size_t needB = (size_t)N_DIM * K_DIM * sizeof(unsigned short); //  32 MB

    if (ws_size >= needA + needB) {
        unsigned short* xb = (unsigned short*)d_ws;
        unsigned short* wt = (unsigned short*)((char*)d_ws + needA);

        long chunks = (long)M_DIM * K_DIM / 8;   // 8,388,608
        cvt_x_tile_kernel<<<(unsigned)(chunks / 256), 256, 0, stream>>>(x, xb);
        cvt_wt_tile_kernel<<<dim3(K_DIM / 64, N_DIM / 64), 256, 0, stream>>>(w, wt);
        gemm_kernel<true><<<(M_DIM / 128) * (N_DIM / 128), 256, 0, stream>>>(xb, wt, bias, out);
    } else {
        gemm_kernel<false><<<(M_DIM / 128) * (N_DIM / 128), 256, 0, stream>>>(x, w, bias, out);
    }
}

// Round 4
// 604.727 us; speedup vs baseline: 1.5657x; 1.4019x over previous
//
#include <hip/hip_runtime.h>
#include <hip/hip_bf16.h>
#include <cstdint>
#include <cstddef>

#define M_DIM 16384
#define K_DIM 4096
#define N_DIM 4096

// Workspace layout (unchanged from r2, verified conflict-free):
// tile = 128 rows x 64 k bf16, 1024 chunks of 16B; chunk (r, c_store) holds
// logical k-chunk c_data = c_store ^ (r&7) of row r.
// A tiles [mt 0..127][kt 0..63]; B tiles [nt 0..31][kt 0..63].

typedef __attribute__((ext_vector_type(8))) short bf16x8;
typedef __attribute__((ext_vector_type(4))) float f32x4;

static __device__ __forceinline__ unsigned short f2bf(float f) {
    union { float f; unsigned int u; } v;
    v.f = f;
    unsigned int lsb = (v.u >> 16) & 1u;
    v.u += 0x7fffu + lsb;
    return (unsigned short)(v.u >> 16);
}

// ---------------------------------------------------------------------------
// Kernel 1: x (M x K fp32) -> xb tiled+swizzled bf16.
// ---------------------------------------------------------------------------
__global__ __launch_bounds__(256) void cvt_x_tile_kernel(const float* __restrict__ x,
                                                         unsigned short* __restrict__ xb) {
    long F = (long)blockIdx.x * 256 + threadIdx.x;
    long tile = F >> 10;
    int within = (int)(F & 1023);
    int r = within >> 3;
    int c_store = within & 7;
    int mt = (int)(tile >> 6);
    int kt = (int)(tile & 63);
    int c_data = c_store ^ (r & 7);
    size_t row = (size_t)mt * 128 + r;
    size_t col = (size_t)kt * 64 + c_data * 8;
    const float4* ps = reinterpret_cast<const float4*>(&x[row * K_DIM + col]);
    float4 a = ps[0], b = ps[1];
    bf16x8 o;
    o[0] = (short)f2bf(a.x); o[1] = (short)f2bf(a.y);
    o[2] = (short)f2bf(a.z); o[3] = (short)f2bf(a.w);
    o[4] = (short)f2bf(b.x); o[5] = (short)f2bf(b.y);
    o[6] = (short)f2bf(b.z); o[7] = (short)f2bf(b.w);
    *reinterpret_cast<bf16x8*>(&xb[F * 8]) = o;
}

// ---------------------------------------------------------------------------
// Kernel 2: W (K x N fp32) -> W^T tiled+swizzled bf16 (N-major tiles).
// ---------------------------------------------------------------------------
__global__ __launch_bounds__(256) void cvt_wt_tile_kernel(const float* __restrict__ W,
                                                          unsigned short* __restrict__ WT) {
    __shared__ float tile[64][65];
    int k0 = blockIdx.x * 64;
    int n0 = blockIdx.y * 64;
    int t = threadIdx.x;

    int c4 = (t & 15) * 4;
    int rr = t >> 4;
#pragma unroll
    for (int p = 0; p < 4; ++p) {
        int kk = rr + p * 16;
        float4 v = *reinterpret_cast<const float4*>(&W[(size_t)(k0 + kk) * N_DIM + n0 + c4]);
        tile[kk][c4 + 0] = v.x;
        tile[kk][c4 + 1] = v.y;
        tile[kk][c4 + 2] = v.z;
        tile[kk][c4 + 3] = v.w;
    }
    __syncthreads();

    int c_data = t & 7;
    int ck = c_data * 8;
    int rn = t >> 3;
    int kt = blockIdx.x;
#pragma unroll
    for (int p = 0; p < 2; ++p) {
        int nn = rn + p * 32;
        int n_g = n0 + nn;
        int nt = n_g >> 7;
        int r = n_g & 127;
        int c_store = c_data ^ (r & 7);
        bf16x8 o;
#pragma unroll
        for (int j = 0; j < 8; ++j) o[j] = (short)f2bf(tile[ck + j][nn]);
        size_t dst = (((size_t)nt * 64 + kt) << 13) + r * 64 + c_store * 8;
        *reinterpret_cast<bf16x8*>(&WT[dst]) = o;
    }
}

// ---------------------------------------------------------------------------
// 8-phase 256^2 GEMM (m201 template, plain HIP): BM=BN=256, BK=64, 512 thr,
// 8 waves (2M x 4N). Per phase: one 128x128 C-quadrant over K=64 (16 MFMA/wave).
// Counted vmcnt(6), 1 half-tile staged per phase, >=1-phase overwrite margin.
// ---------------------------------------------------------------------------
__global__ __launch_bounds__(512, 2) void gemm8_kernel(const unsigned short* __restrict__ A,
                                                       const unsigned short* __restrict__ B,
                                                       const float* __restrict__ bias,
                                                       float* __restrict__ C) {
    __shared__ unsigned short As[4 * 8192];   // [dbuf][half][128][64]
    __shared__ unsigned short Bs[4 * 8192];

    int bid = blockIdx.x;
    int swz = (bid & 7) * 128 + (bid >> 3);   // grid 1024 % 8 == 0 -> bijective
    int bm = swz >> 4;    // 0..63
    int bn = swz & 15;    // 0..15

    int t = threadIdx.x;
    int l = t & 63;
    int wid = t >> 6;
    int wr = wid >> 2;    // 0..1
    int wc = wid & 3;     // 0..3
    int lr = l & 15;
    int lg = l >> 4;

    // swizzled k-chunk element offsets for ks = 0,1 (row&7 == lr&7 always)
    int coff0 = ((0 + lg) ^ (lr & 7)) * 8;
    int coff1 = ((4 + lg) ^ (lr & 7)) * 8;
    int rowA = wr * 64 + lr;   // + mq*16
    int rowB = wc * 32 + lr;   // + nq*16

    auto aSrc = [&](int h, int kt) {
        return A + ((size_t)((2 * bm + h) * 64 + kt) << 13);
    };
    auto bSrc = [&](int h, int kt) {
        return B + ((size_t)((2 * bn + h) * 64 + kt) << 13);
    };
    auto stage_half = [&](unsigned short* dst, const unsigned short* src) {
        __builtin_amdgcn_global_load_lds(
            (const __attribute__((address_space(1))) unsigned int*)(src + (size_t)t * 8),
            (__attribute__((address_space(3))) unsigned int*)(dst + (size_t)t * 8), 16, 0, 0);
        __builtin_amdgcn_global_load_lds(
            (const __attribute__((address_space(1))) unsigned int*)(src + (size_t)(512 + t) * 8),
            (__attribute__((address_space(3))) unsigned int*)(dst + (size_t)(512 + t) * 8), 16, 0, 0);
    };

    f32x4 acc[4][4][2];   // [quadrant-phase][mq][nq]
#pragma unroll
    for (int p = 0; p < 4; ++p)
#pragma unroll
        for (int m = 0; m < 4; ++m)
#pragma unroll
            for (int n = 0; n < 2; ++n) acc[p][m][n] = (f32x4)(0.0f);

    // Prologue: tile0 complete + tile1 {A0, B1, A1}; B0 of tile1 staged at p1 of kt=0.
    stage_half(&As[0 * 8192], aSrc(0, 0));
    stage_half(&As[1 * 8192], aSrc(1, 0));
    stage_half(&Bs[0 * 8192], bSrc(0, 0));
    stage_half(&Bs[1 * 8192], bSrc(1, 0));
    stage_half(&As[2 * 8192], aSrc(0, 1));
    stage_half(&Bs[3 * 8192], bSrc(1, 1));
    stage_half(&As[3 * 8192], aSrc(1, 1));
    asm volatile("s_waitcnt vmcnt(6)" ::: "memory");   // tile0 landed
    __builtin_amdgcn_s_barrier();

    for (int kt = 0; kt < 64; ++kt) {
        int d = kt & 1;
        const unsigned short* A0p = &As[(d * 2 + 0) * 8192];
        const unsigned short* A1p = &As[(d * 2 + 1) * 8192];
        const unsigned short* B0p = &Bs[(d * 2 + 0) * 8192];
        const unsigned short* B1p = &Bs[(d * 2 + 1) * 8192];

        bf16x8 a[4][2], b0[2][2], b1[2][2];

        // ---- phase 1: quadrant (0,0) — read A0 + B0; stage B0 of kt+1
#pragma unroll
        for (int mq = 0; mq < 4; ++mq) {
            a[mq][0] = *reinterpret_cast<const bf16x8*>(&A0p[(rowA + mq * 16) * 64 + coff0]);
            a[mq][1] = *reinterpret_cast<const bf16x8*>(&A0p[(rowA + mq * 16) * 64 + coff1]);
        }
#pragma unroll
        for (int nq = 0; nq < 2; ++nq) {
            b0[nq][0] = *reinterpret_cast<const bf16x8*>(&B0p[(rowB + nq * 16) * 64 + coff0]);
            b0[nq][1] = *reinterpret_cast<const bf16x8*>(&B0p[(rowB + nq * 16) * 64 + coff1]);
        }
        if (kt + 1 < 64) stage_half(&Bs[(((kt + 1) & 1) * 2 + 0) * 8192], bSrc(0, kt + 1));
        __builtin_amdgcn_s_barrier();
        asm volatile("s_waitcnt lgkmcnt(0)" ::: "memory");
        __builtin_amdgcn_s_setprio(1);
#pragma unroll
        for (int mq = 0; mq < 4; ++mq)
#pragma unroll
            for (int nq = 0; nq < 2; ++nq) {
                acc[0][mq][nq] = __builtin_amdgcn_mfma_f32_16x16x32_bf16(a[mq][0], b0[nq][0],
                                                                         acc[0][mq][nq], 0, 0, 0);
                acc[0][mq][nq] = __builtin_amdgcn_mfma_f32_16x16x32_bf16(a[mq][1], b0[nq][1],
                                                                         acc[0][mq][nq], 0, 0, 0);
            }
        __builtin_amdgcn_s_setprio(0);
        __builtin_amdgcn_s_barrier();

        // ---- phase 2: quadrant (0,1) — reuse A0 regs, read B1; stage A0 of kt+2
#pragma unroll
        for (int nq = 0; nq < 2; ++nq) {
            b1[nq][0] = *reinterpret_cast<const bf16x8*>(&B1p[(rowB + nq * 16) * 64 + coff0]);
            b1[nq][1] = *reinterpret_cast<const bf16x8*>(&B1p[(rowB + nq * 16) * 64 + coff1]);
        }
        if (kt + 2 < 64) stage_half(&As[(d * 2 + 0) * 8192], aSrc(0, kt + 2));
        __builtin_amdgcn_s_barrier();
        asm volatile("s_waitcnt lgkmcnt(0)" ::: "memory");
        __builtin_amdgcn_s_setprio(1);
#pragma unroll
        for (int mq = 0; mq < 4; ++mq)
#pragma unroll
            for (int nq = 0; nq < 2; ++nq) {
                acc[1][mq][nq] = __builtin_amdgcn_mfma_f32_16x16x32_bf16(a[mq][0], b1[nq][0],
                                                                         acc[1][mq][nq], 0, 0, 0);
                acc[1][mq][nq] = __builtin_amdgcn_mfma_f32_16x16x32_bf16(a[mq][1], b1[nq][1],
                                                                         acc[1][mq][nq], 0, 0, 0);
            }
        __builtin_amdgcn_s_setprio(0);
        __builtin_amdgcn_s_barrier();

        // ---- phase 3: quadrant (1,1) — read A1 (overwrite a), reuse B1; stage B1 of kt+2
#pragma unroll
        for (int mq = 0; mq < 4; ++mq) {
            a[mq][0] = *reinterpret_cast<const bf16x8*>(&A1p[(rowA + mq * 16) * 64 + coff0]);
            a[mq][1] = *reinterpret_cast<const bf16x8*>(&A1p[(rowA + mq * 16) * 64 + coff1]);
        }
        if (kt + 2 < 64) stage_half(&Bs[(d * 2 + 1) * 8192], bSrc(1, kt + 2));
        __builtin_amdgcn_s_barrier();
        asm volatile("s_waitcnt lgkmcnt(0)" ::: "memory");
        __builtin_amdgcn_s_setprio(1);
#pragma unroll
        for (int mq = 0; mq < 4; ++mq)
#pragma unroll
            for (int nq = 0; nq < 2; ++nq) {
                acc[2][mq][nq] = __builtin_amdgcn_mfma_f32_16x16x32_bf16(a[mq][0], b1[nq][0],
                                                                         acc[2][mq][nq], 0, 0, 0);
                acc[2][mq][nq] = __builtin_amdgcn_mfma_f32_16x16x32_bf16(a[mq][1], b1[nq][1],
                                                                         acc[2][mq][nq], 0, 0, 0);
            }
        __builtin_amdgcn_s_setprio(0);
        __builtin_amdgcn_s_barrier();

        // ---- phase 4: quadrant (1,0) — reuse A1 + kept B0 regs; stage A1 of kt+2
        if (kt + 2 < 64) stage_half(&As[(d * 2 + 1) * 8192], aSrc(1, kt + 2));
        __builtin_amdgcn_s_barrier();
        __builtin_amdgcn_s_setprio(1);
#pragma unroll
        for (int mq = 0; mq < 4; ++mq)
#pragma unroll
            for (int nq = 0; nq < 2; ++nq) {
                acc[3][mq][nq] = __builtin_amdgcn_mfma_f32_16x16x32_bf16(a[mq][0], b0[nq][0],
                                                                         acc[3][mq][nq], 0, 0, 0);
                acc[3][mq][nq] = __builtin_amdgcn_mfma_f32_16x16x32_bf16(a[mq][1], b0[nq][1],
                                                                         acc[3][mq][nq], 0, 0, 0);
            }
        __builtin_amdgcn_s_setprio(0);
        if (kt < 62) {
            asm volatile("s_waitcnt vmcnt(6)" ::: "memory");   // tile kt+1 fully landed
        } else if (kt == 62) {
            asm volatile("s_waitcnt vmcnt(0)" ::: "memory");   // drain for final tile
        }
        __builtin_amdgcn_s_barrier();
    }

    // Epilogue: C/D layout col = lane&15, row = (lane>>4)*4 + reg
    const int qmh[4] = {0, 0, 1, 1};
    const int qnh[4] = {0, 1, 1, 0};
#pragma unroll
    for (int ph = 0; ph < 4; ++ph)
#pragma unroll
        for (int nq = 0; nq < 2; ++nq) {
            int col = bn * 256 + qnh[ph] * 128 + wc * 32 + nq * 16 + lr;
            float bv = bias[col];
#pragma unroll
            for (int mq = 0; mq < 4; ++mq)
#pragma unroll
                for (int j = 0; j < 4; ++j) {
                    int row = bm * 256 + qmh[ph] * 128 + wr * 64 + mq * 16 + lg * 4 + j;
                    C[(size_t)row * N_DIM + col] = acc[ph][mq][nq][j] + bv;
                }
        }
}

// ---------------------------------------------------------------------------
// Fallback 128^2 GEMM (r2's verified kernel), used only if ws is too small.
// ---------------------------------------------------------------------------
__global__ __launch_bounds__(256) void gemm_fb_kernel(const float* __restrict__ Af,
                                                      const float* __restrict__ Wf,
                                                      const float* __restrict__ bias,
                                                      float* __restrict__ C) {
    __shared__ unsigned short As[128 * 64];
    __shared__ unsigned short Bs[128 * 64];

    int bid = blockIdx.x;
    int swz = (bid & 7) * (4096 / 8) + (bid >> 3);
    int nt = swz & 31;
    int mt = swz >> 5;
    int m0 = mt * 128;
    int n0 = nt * 128;

    int t = threadIdx.x;
    int l = t & 63;
    int wid = t >> 6;
    int wr = wid >> 1;
    int wc = wid & 1;
    int lr = l & 15;
    int lg = l >> 4;

    f32x4 acc[4][4];
#pragma unroll
    for (int m = 0; m < 4; ++m)
#pragma unroll
        for (int n = 0; n < 4; ++n) acc[m][n] = (f32x4)(0.0f);

    for (int kt = 0; kt < 64; ++kt) {
#pragma unroll
        for (int i = 0; i < 4; ++i) {
            int off = (i * 256 + t) * 8;
            int row = off >> 6;
            int col = off & 63;
            const float4* pa =
                reinterpret_cast<const float4*>(&Af[(size_t)(m0 + row) * K_DIM + kt * 64 + col]);
            float4 a = pa[0], b = pa[1];
            bf16x8 rg;
            rg[0] = (short)f2bf(a.x); rg[1] = (short)f2bf(a.y);
            rg[2] = (short)f2bf(a.z); rg[3] = (short)f2bf(a.w);
            rg[4] = (short)f2bf(b.x); rg[5] = (short)f2bf(b.y);
            rg[6] = (short)f2bf(b.z); rg[7] = (short)f2bf(b.w);
            *reinterpret_cast<bf16x8*>(&As[off]) = rg;
        }
#pragma unroll
        for (int i = 0; i < 4; ++i) {
            int off = (i * 256 + t) * 8;
            int k = off >> 7;
            int n = off & 127;
            const float4* pw =
                reinterpret_cast<const float4*>(&Wf[(size_t)(kt * 64 + k) * N_DIM + n0 + n]);
            float4 a = pw[0], b = pw[1];
            float v[8] = {a.x, a.y, a.z, a.w, b.x, b.y, b.z, b.w};
#pragma unroll
            for (int j = 0; j < 8; ++j) Bs[(n + j) * 64 + k] = f2bf(v[j]);
        }
        __syncthreads();

#pragma unroll
        for (int ks = 0; ks < 2; ++ks) {
            bf16x8 af[4], bfr[4];
            int c = (ks << 2) | lg;
#pragma unroll
            for (int m = 0; m < 4; ++m)
                af[m] = *reinterpret_cast<const bf16x8*>(&As[(wr * 64 + m * 16 + lr) * 64 + c * 8]);
#pragma unroll
            for (int n = 0; n < 4; ++n)
                bfr[n] = *reinterpret_cast<const bf16x8*>(&Bs[(wc * 64 + n * 16 + lr) * 64 + c * 8]);
#pragma unroll
            for (int m = 0; m < 4; ++m)
#pragma unroll
                for (int n = 0; n < 4; ++n)
                    acc[m][n] = __builtin_amdgcn_mfma_f32_16x16x32_bf16(af[m], bfr[n],
                                                                        acc[m][n], 0, 0, 0);
        }
        __syncthreads();
    }

#pragma unroll
    for (int n = 0; n < 4; ++n) {
        int col = n0 + wc * 64 + n * 16 + lr;
        float bv = bias[col];
#pragma unroll
        for (int m = 0; m < 4; ++m)
#pragma unroll
            for (int j = 0; j < 4; ++j) {
                int row = m0 + wr * 64 + m * 16 + lg * 4 + j;
                C[(size_t)row * N_DIM + col] = acc[m][n][j] + bv;
            }
    }
}

// ---------------------------------------------------------------------------
extern "C" void kernel_launch(void* const* d_in, const int* in_sizes, int n_in,
                              void* d_out, int out_size, void* d_ws, size_t ws_size,
                              hipStream_t stream) {
    const float* x    = (const float*)d_in[0];
    const float* w    = (const float*)d_in[1];
    const float* bias = (const float*)d_in[2];
    float* out = (float*)d_out;

    const size_t needA = (size_t)M_DIM * K_DIM * sizeof(unsigned short); // 128 MB
    const size_t needB = (size_t)N_DIM * K_DIM * sizeof(unsigned short); //  32 MB

    if (ws_size >= needA + needB) {
        unsigned short* xb = (unsigned short*)d_ws;
        unsigned short* wt = (unsigned short*)((char*)d_ws + needA);

        long chunks = (long)M_DIM * K_DIM / 8;
        cvt_x_tile_kernel<<<(unsigned)(chunks / 256), 256, 0, stream>>>(x, xb);
        cvt_wt_tile_kernel<<<dim3(K_DIM / 64, N_DIM / 64), 256, 0, stream>>>(w, wt);
        gemm8_kernel<<<(M_DIM / 256) * (N_DIM / 256), 512, 0, stream>>>(xb, wt, bias, out);
    } else {
        gemm_fb_kernel<<<(M_DIM / 128) * (N_DIM / 128), 256, 0, stream>>>(x, w, bias, out);
    }
}

// Round 5
// 574.379 us; speedup vs baseline: 1.6484x; 1.0528x over previous
//
#include <hip/hip_runtime.h>
#include <hip/hip_bf16.h>
#include <cstdint>
#include <cstddef>

#define M_DIM 16384
#define K_DIM 4096
#define N_DIM 4096
#define NKT   128   // K / 32

// Workspace layout (new for BK=32 ring kernel):
// A: per (mt 0..127, kt 0..127): 8KB piece = 512 chunks of 16B.
//    chunk (r 0..127, c_store 0..3) holds logical row mt*128+r,
//    k-chunk c_data = c_store ^ ((r>>1)&3) of k-step kt (k = kt*32 + c_data*8).
// B: per (nt2 0..15, kt 0..127): 16KB piece = 1024 chunks; rows r 0..255 are n
//    within the 256-col tile; same swizzle formula.
// Staging is then a pure linear 16B-per-lane copy (global_load_lds-compatible)
// and LDS reads at chunk c_store = lg ^ ((r>>1)&3) are bank-conflict-free
// (16 lanes span all 32 banks via addr[6]=r&1, addr[5:4]=c_store; 2-way free).

typedef __attribute__((ext_vector_type(8))) short bf16x8;
typedef __attribute__((ext_vector_type(4))) float f32x4;

static __device__ __forceinline__ unsigned short f2bf(float f) {
    union { float f; unsigned int u; } v;
    v.f = f;
    unsigned int lsb = (v.u >> 16) & 1u;
    v.u += 0x7fffu + lsb;
    return (unsigned short)(v.u >> 16);
}

// ---------------------------------------------------------------------------
// Kernel 1: x (M x K fp32) -> A-workspace (tiled+swizzled bf16), 1 chunk/thread.
// F = ((mt*128 + kt)*512 + r*4 + c_store)  [8,388,608 chunks total]
// ---------------------------------------------------------------------------
__global__ __launch_bounds__(256) void cvt_x_tile_kernel(const float* __restrict__ x,
                                                         unsigned short* __restrict__ xb) {
    unsigned int F = blockIdx.x * 256 + threadIdx.x;
    int c_store = F & 3;
    int r       = (F >> 2) & 127;
    int kt      = (F >> 9) & 127;
    int mt      = F >> 16;
    int c_data  = c_store ^ ((r >> 1) & 3);
    size_t row = (size_t)mt * 128 + r;
    size_t k   = (size_t)kt * 32 + c_data * 8;
    const float4* ps = reinterpret_cast<const float4*>(&x[row * K_DIM + k]);
    float4 a = ps[0], b = ps[1];
    bf16x8 o;
    o[0] = (short)f2bf(a.x); o[1] = (short)f2bf(a.y);
    o[2] = (short)f2bf(a.z); o[3] = (short)f2bf(a.w);
    o[4] = (short)f2bf(b.x); o[5] = (short)f2bf(b.y);
    o[6] = (short)f2bf(b.z); o[7] = (short)f2bf(b.w);
    *reinterpret_cast<bf16x8*>(&xb[(size_t)F * 8]) = o;
}

// ---------------------------------------------------------------------------
// Kernel 2: W (K x N fp32) -> B-workspace (transposed, tiled+swizzled bf16).
// 64x64 fp32 LDS transpose tile, +1 pad.
// ---------------------------------------------------------------------------
__global__ __launch_bounds__(256) void cvt_wt_tile_kernel(const float* __restrict__ W,
                                                          unsigned short* __restrict__ WT) {
    __shared__ float tile[64][65];
    int k0 = blockIdx.x * 64;   // bx 0..63
    int n0 = blockIdx.y * 64;   // by 0..63
    int t = threadIdx.x;

    int c4 = (t & 15) * 4;
    int rr = t >> 4;
#pragma unroll
    for (int p = 0; p < 4; ++p) {
        int kk = rr + p * 16;
        float4 v = *reinterpret_cast<const float4*>(&W[(size_t)(k0 + kk) * N_DIM + n0 + c4]);
        tile[kk][c4 + 0] = v.x;
        tile[kk][c4 + 1] = v.y;
        tile[kk][c4 + 2] = v.z;
        tile[kk][c4 + 3] = v.w;
    }
    __syncthreads();

    int c  = t & 7;     // k-chunk within 64 (0..7)
    int rn = t >> 3;    // 0..31
#pragma unroll
    for (int p = 0; p < 2; ++p) {
        int nn = rn + p * 32;
        int n_g = n0 + nn;
        int nt2 = n_g >> 8;
        int r   = n_g & 255;
        int kt  = blockIdx.x * 2 + (c >> 2);
        int c_store = (c & 3) ^ ((r >> 1) & 3);
        bf16x8 o;
#pragma unroll
        for (int j = 0; j < 8; ++j) o[j] = (short)f2bf(tile[c * 8 + j][nn]);
        size_t dst = ((size_t)(nt2 * 128 + kt) * 1024 + r * 4 + c_store) * 8;
        *reinterpret_cast<bf16x8*>(&WT[dst]) = o;
    }
}

// ---------------------------------------------------------------------------
// GEMM: BM=128, BN=256, BK=32, 512 thr = 8 waves (2M x 4N), 64x64 per wave.
// 3-deep LDS ring (72 KiB -> 2 blocks/CU), 1 barrier + counted vmcnt(3)/K-step,
// 16 MFMA + 8 balanced ds_read_b128 per K-step. Compiler schedules lgkm waits.
// ---------------------------------------------------------------------------
__global__ __launch_bounds__(512, 4) void gemm32_kernel(const unsigned short* __restrict__ A,
                                                        const unsigned short* __restrict__ B,
                                                        const float* __restrict__ bias,
                                                        float* __restrict__ C) {
    __shared__ unsigned short lds[3 * 12288];   // slot: A[128*32] + B[256*32]

    int bid = blockIdx.x;
    int swz = (bid & 7) * 256 + (bid >> 3);   // grid 2048 % 8 == 0 -> bijective
    int bm = swz >> 4;    // 0..127
    int bn = swz & 15;    // 0..15

    int t = threadIdx.x;
    int l = t & 63;
    int wid = t >> 6;
    int wr = wid >> 2;    // 0..1
    int wc = wid & 3;     // 0..3
    int lr = l & 15;
    int lg = l >> 4;

    int swzc  = (lg ^ ((lr >> 1) & 3)) * 8;   // swizzled k-chunk (shorts)
    int rowA0 = wr * 64 + lr;                 // + mq*16
    int rowB0 = wc * 64 + lr;                 // + nq*16

    const unsigned short* Abase = A + (size_t)bm * NKT * 4096;
    const unsigned short* Bbase = B + (size_t)bn * NKT * 8192;

    auto stage = [&](int slot, int kt) {
        const unsigned short* as = Abase + (size_t)kt * 4096;
        const unsigned short* bs = Bbase + (size_t)kt * 8192;
        unsigned short* da = &lds[slot * 12288];
        unsigned short* db = da + 4096;
        __builtin_amdgcn_global_load_lds(
            (const __attribute__((address_space(1))) unsigned int*)(as + (size_t)t * 8),
            (__attribute__((address_space(3))) unsigned int*)(da + (size_t)t * 8), 16, 0, 0);
        __builtin_amdgcn_global_load_lds(
            (const __attribute__((address_space(1))) unsigned int*)(bs + (size_t)t * 8),
            (__attribute__((address_space(3))) unsigned int*)(db + (size_t)t * 8), 16, 0, 0);
        __builtin_amdgcn_global_load_lds(
            (const __attribute__((address_space(1))) unsigned int*)(bs + (size_t)(512 + t) * 8),
            (__attribute__((address_space(3))) unsigned int*)(db + (size_t)(512 + t) * 8), 16, 0, 0);
    };

    f32x4 acc[4][4];
#pragma unroll
    for (int m = 0; m < 4; ++m)
#pragma unroll
        for (int n = 0; n < 4; ++n) acc[m][n] = (f32x4)(0.0f);

    // Prologue: tiles 0 and 1 in flight; wait tile0 (leave tile1's 3 loads).
    stage(0, 0);
    stage(1, 1);
    asm volatile("s_waitcnt vmcnt(3)" ::: "memory");
    __builtin_amdgcn_s_barrier();
    asm volatile("" ::: "memory");

    int rs = 0;
    for (int kt = 0; kt < NKT; ++kt) {
        int wslot = rs + 2; if (wslot >= 3) wslot -= 3;
        if (kt + 2 < NKT) stage(wslot, kt + 2);   // uniform guard

        const unsigned short* Ap = &lds[rs * 12288];
        const unsigned short* Bp = Ap + 4096;
        bf16x8 a[4], b[4];
#pragma unroll
        for (int mq = 0; mq < 4; ++mq)
            a[mq] = *reinterpret_cast<const bf16x8*>(&Ap[(rowA0 + mq * 16) * 32 + swzc]);
#pragma unroll
        for (int nq = 0; nq < 4; ++nq)
            b[nq] = *reinterpret_cast<const bf16x8*>(&Bp[(rowB0 + nq * 16) * 32 + swzc]);

#pragma unroll
        for (int mq = 0; mq < 4; ++mq)
#pragma unroll
            for (int nq = 0; nq < 4; ++nq)
                acc[mq][nq] = __builtin_amdgcn_mfma_f32_16x16x32_bf16(a[mq], b[nq],
                                                                      acc[mq][nq], 0, 0, 0);

        if (kt < NKT - 2) {
            asm volatile("s_waitcnt vmcnt(3)" ::: "memory");   // tile kt+1 landed
        } else if (kt == NKT - 2) {
            asm volatile("s_waitcnt vmcnt(0)" ::: "memory");   // drain for last tile
        }
        __builtin_amdgcn_s_barrier();
        asm volatile("" ::: "memory");
        rs = (rs == 2) ? 0 : rs + 1;
    }

    // Epilogue: C/D layout col = lane&15, row = (lane>>4)*4 + reg
#pragma unroll
    for (int nq = 0; nq < 4; ++nq) {
        int col = bn * 256 + wc * 64 + nq * 16 + lr;
        float bv = bias[col];
#pragma unroll
        for (int mq = 0; mq < 4; ++mq)
#pragma unroll
            for (int j = 0; j < 4; ++j) {
                int row = bm * 128 + wr * 64 + mq * 16 + lg * 4 + j;
                C[(size_t)row * N_DIM + col] = acc[mq][nq][j] + bv;
            }
    }
}

// ---------------------------------------------------------------------------
// Fallback 128^2 GEMM (r2's verified kernel), used only if ws is too small.
// ---------------------------------------------------------------------------
__global__ __launch_bounds__(256) void gemm_fb_kernel(const float* __restrict__ Af,
                                                      const float* __restrict__ Wf,
                                                      const float* __restrict__ bias,
                                                      float* __restrict__ C) {
    __shared__ unsigned short As[128 * 64];
    __shared__ unsigned short Bs[128 * 64];

    int bid = blockIdx.x;
    int swz = (bid & 7) * (4096 / 8) + (bid >> 3);
    int nt = swz & 31;
    int mt = swz >> 5;
    int m0 = mt * 128;
    int n0 = nt * 128;

    int t = threadIdx.x;
    int l = t & 63;
    int wid = t >> 6;
    int wr = wid >> 1;
    int wc = wid & 1;
    int lr = l & 15;
    int lg = l >> 4;

    f32x4 acc[4][4];
#pragma unroll
    for (int m = 0; m < 4; ++m)
#pragma unroll
        for (int n = 0; n < 4; ++n) acc[m][n] = (f32x4)(0.0f);

    for (int kt = 0; kt < 64; ++kt) {
#pragma unroll
        for (int i = 0; i < 4; ++i) {
            int off = (i * 256 + t) * 8;
            int row = off >> 6;
            int col = off & 63;
            const float4* pa =
                reinterpret_cast<const float4*>(&Af[(size_t)(m0 + row) * K_DIM + kt * 64 + col]);
            float4 a = pa[0], b = pa[1];
            bf16x8 rg;
            rg[0] = (short)f2bf(a.x); rg[1] = (short)f2bf(a.y);
            rg[2] = (short)f2bf(a.z); rg[3] = (short)f2bf(a.w);
            rg[4] = (short)f2bf(b.x); rg[5] = (short)f2bf(b.y);
            rg[6] = (short)f2bf(b.z); rg[7] = (short)f2bf(b.w);
            *reinterpret_cast<bf16x8*>(&As[off]) = rg;
        }
#pragma unroll
        for (int i = 0; i < 4; ++i) {
            int off = (i * 256 + t) * 8;
            int k = off >> 7;
            int n = off & 127;
            const float4* pw =
                reinterpret_cast<const float4*>(&Wf[(size_t)(kt * 64 + k) * N_DIM + n0 + n]);
            float4 a = pw[0], b = pw[1];
            float v[8] = {a.x, a.y, a.z, a.w, b.x, b.y, b.z, b.w};
#pragma unroll
            for (int j = 0; j < 8; ++j) Bs[(n + j) * 64 + k] = f2bf(v[j]);
        }
        __syncthreads();

#pragma unroll
        for (int ks = 0; ks < 2; ++ks) {
            bf16x8 af[4], bfr[4];
            int c = (ks << 2) | lg;
#pragma unroll
            for (int m = 0; m < 4; ++m)
                af[m] = *reinterpret_cast<const bf16x8*>(&As[(wr * 64 + m * 16 + lr) * 64 + c * 8]);
#pragma unroll
            for (int n = 0; n < 4; ++n)
                bfr[n] = *reinterpret_cast<const bf16x8*>(&Bs[(wc * 64 + n * 16 + lr) * 64 + c * 8]);
#pragma unroll
            for (int m = 0; m < 4; ++m)
#pragma unroll
                for (int n = 0; n < 4; ++n)
                    acc[m][n] = __builtin_amdgcn_mfma_f32_16x16x32_bf16(af[m], bfr[n],
                                                                        acc[m][n], 0, 0, 0);
        }
        __syncthreads();
    }

#pragma unroll
    for (int n = 0; n < 4; ++n) {
        int col = n0 + wc * 64 + n * 16 + lr;
        float bv = bias[col];
#pragma unroll
        for (int m = 0; m < 4; ++m)
#pragma unroll
            for (int j = 0; j < 4; ++j) {
                int row = m0 + wr * 64 + m * 16 + lg * 4 + j;
                C[(size_t)row * N_DIM + col] = acc[m][n][j] + bv;
            }
    }
}

// ---------------------------------------------------------------------------
extern "C" void kernel_launch(void* const* d_in, const int* in_sizes, int n_in,
                              void* d_out, int out_size, void* d_ws, size_t ws_size,
                              hipStream_t stream) {
    const float* x    = (const float*)d_in[0];
    const float* w    = (const float*)d_in[1];
    const float* bias = (const float*)d_in[2];
    float* out = (float*)d_out;

    const size_t needA = (size_t)M_DIM * K_DIM * sizeof(unsigned short); // 128 MB
    const size_t needB = (size_t)N_DIM * K_DIM * sizeof(unsigned short); //  32 MB

    if (ws_size >= needA + needB) {
        unsigned short* xb = (unsigned short*)d_ws;
        unsigned short* wt = (unsigned short*)((char*)d_ws + needA);

        long chunks = (long)M_DIM * K_DIM / 8;   // 8,388,608
        cvt_x_tile_kernel<<<(unsigned)(chunks / 256), 256, 0, stream>>>(x, xb);
        cvt_wt_tile_kernel<<<dim3(K_DIM / 64, N_DIM / 64), 256, 0, stream>>>(w, wt);
        gemm32_kernel<<<(M_DIM / 128) * (N_DIM / 256), 512, 0, stream>>>(xb, wt, bias, out);
    } else {
        gemm_fb_kernel<<<(M_DIM / 128) * (N_DIM / 128), 256, 0, stream>>>(x, w, bias, out);
    }
}

// Round 6
// 373.274 us; speedup vs baseline: 2.5365x; 1.5388x over previous
//
#include <hip/hip_runtime.h>
#include <hip/hip_bf16.h>
#include <cstdint>
#include <cstddef>

#define M_DIM 16384
#define K_DIM 4096
#define N_DIM 4096
#define NKT   64    // K / 64 (i8 MFMA K=64 per step)

// i8 workspace layout:
// A: per (mt 0..127, kt 0..63): 8KB piece = 128 rows x 64 i8.
//    chunk (r, c_store 0..3) [16B] holds k-chunk c_data = c_store ^ ((r>>1)&3),
//    i.e. k = kt*64 + c_data*16 .. +15, of row mt*128+r.
// B: per (nt2 0..15, kt 0..63): 16KB piece = 256 rows(n) x 64 i8, same swizzle.
// scales: 16384 floats (per-M-row absmax/127).
// GEMM staging is pure linear 16B/lane (global_load_lds); LDS fragment reads at
// c_store = lg ^ ((r>>1)&3) are bank-conflict-free (verified 0 conflicts in r5,
// identical address bits for 64B i8 rows).

typedef __attribute__((ext_vector_type(4))) int   i32x4;
typedef __attribute__((ext_vector_type(4))) float f32x4;
typedef __attribute__((ext_vector_type(8))) short bf16x8;

static __device__ __forceinline__ unsigned short f2bf(float f) {
    union { float f; unsigned int u; } v;
    v.f = f;
    unsigned int lsb = (v.u >> 16) & 1u;
    v.u += 0x7fffu + lsb;
    return (unsigned short)(v.u >> 16);
}

// ---------------------------------------------------------------------------
// Kernel 1: per-row quantize x -> i8 workspace + scales. One block per M-row;
// thread t holds floats [t*16, t*16+16) = exactly one 16B output chunk.
// ---------------------------------------------------------------------------
__global__ __launch_bounds__(256) void quant_x_kernel(const float* __restrict__ x,
                                                      signed char* __restrict__ xq,
                                                      float* __restrict__ scales) {
    int row = blockIdx.x;
    int t = threadIdx.x;
    const float4* px = reinterpret_cast<const float4*>(x + (size_t)row * K_DIM);
    float4 v0 = px[t * 4 + 0], v1 = px[t * 4 + 1], v2 = px[t * 4 + 2], v3 = px[t * 4 + 3];
    float f[16] = {v0.x, v0.y, v0.z, v0.w, v1.x, v1.y, v1.z, v1.w,
                   v2.x, v2.y, v2.z, v2.w, v3.x, v3.y, v3.z, v3.w};
    float am = 0.0f;
#pragma unroll
    for (int i = 0; i < 16; ++i) am = fmaxf(am, fabsf(f[i]));
#pragma unroll
    for (int off = 32; off >= 1; off >>= 1) am = fmaxf(am, __shfl_xor(am, off));
    __shared__ float wm[4];
    if ((t & 63) == 0) wm[t >> 6] = am;
    __syncthreads();
    float amax = fmaxf(fmaxf(wm[0], wm[1]), fmaxf(wm[2], wm[3]));
    float inv = amax > 0.0f ? 127.0f / amax : 0.0f;
    if (t == 0) scales[row] = amax * (1.0f / 127.0f);

    int w[4];
#pragma unroll
    for (int g = 0; g < 4; ++g) {
        int b0 = (int)fmaxf(-127.0f, fminf(127.0f, rintf(f[g * 4 + 0] * inv)));
        int b1 = (int)fmaxf(-127.0f, fminf(127.0f, rintf(f[g * 4 + 1] * inv)));
        int b2 = (int)fmaxf(-127.0f, fminf(127.0f, rintf(f[g * 4 + 2] * inv)));
        int b3 = (int)fmaxf(-127.0f, fminf(127.0f, rintf(f[g * 4 + 3] * inv)));
        w[g] = (b0 & 255) | ((b1 & 255) << 8) | ((b2 & 255) << 16) | ((b3 & 255) << 24);
    }
    int mt = row >> 7, r = row & 127;
    int kt = t >> 2;
    int cs = (t & 3) ^ ((r >> 1) & 3);
    *reinterpret_cast<int4*>(xq + (size_t)(mt * 64 + kt) * 8192 + r * 64 + cs * 16) =
        make_int4(w[0], w[1], w[2], w[3]);
}

// ---------------------------------------------------------------------------
// Kernel 2: W (K x N fp32, exactly ternary) -> i8 W^T workspace (transposed).
// 64x64 fp32 LDS transpose tile, +1 pad.
// ---------------------------------------------------------------------------
__global__ __launch_bounds__(256) void cvt_wt_i8_kernel(const float* __restrict__ W,
                                                        signed char* __restrict__ WT) {
    __shared__ float tile[64][65];
    int k0 = blockIdx.x * 64;   // kt = blockIdx.x (0..63)
    int n0 = blockIdx.y * 64;
    int t = threadIdx.x;

    int c4 = (t & 15) * 4;
    int rr = t >> 4;
#pragma unroll
    for (int p = 0; p < 4; ++p) {
        int kk = rr + p * 16;
        float4 v = *reinterpret_cast<const float4*>(&W[(size_t)(k0 + kk) * N_DIM + n0 + c4]);
        tile[kk][c4 + 0] = v.x;
        tile[kk][c4 + 1] = v.y;
        tile[kk][c4 + 2] = v.z;
        tile[kk][c4 + 3] = v.w;
    }
    __syncthreads();

    int r_loc = t >> 2;          // n within block (0..63)
    int cd = t & 3;              // k-chunk (0..3)
    int n_g = n0 + r_loc;
    int nt2 = n_g >> 8;
    int r = n_g & 255;
    int kt = blockIdx.x;
    int cs = cd ^ ((r >> 1) & 3);
    int w[4];
#pragma unroll
    for (int g = 0; g < 4; ++g) {
        int b0 = (int)tile[cd * 16 + g * 4 + 0][r_loc];
        int b1 = (int)tile[cd * 16 + g * 4 + 1][r_loc];
        int b2 = (int)tile[cd * 16 + g * 4 + 2][r_loc];
        int b3 = (int)tile[cd * 16 + g * 4 + 3][r_loc];
        w[g] = (b0 & 255) | ((b1 & 255) << 8) | ((b2 & 255) << 16) | ((b3 & 255) << 24);
    }
    *reinterpret_cast<int4*>(WT + (size_t)(nt2 * 64 + kt) * 16384 + r * 64 + cs * 16) =
        make_int4(w[0], w[1], w[2], w[3]);
}

// ---------------------------------------------------------------------------
// GEMM (i8): BM=128, BN=256, BK=64, 512 thr = 8 waves (2M x 4N), 64x64/wave.
// r5-verified ring structure: 3-deep LDS ring (72 KiB -> 2 blocks/CU),
// 1 barrier + counted vmcnt(3) per K-step, 8 ds_read_b128 + 16 MFMA(i8 K=64).
// Epilogue: out = float(acc_i32) * scale[row] + bias[col]  (i32 accum exact).
// ---------------------------------------------------------------------------
__global__ __launch_bounds__(512, 4) void gemm_i8_kernel(const signed char* __restrict__ A,
                                                         const signed char* __restrict__ B,
                                                         const float* __restrict__ bias,
                                                         const float* __restrict__ scales,
                                                         float* __restrict__ C) {
    __shared__ signed char lds[3 * 24576];   // slot: A[128*64] + B[256*64]

    int bid = blockIdx.x;
    int swz = (bid & 7) * 256 + (bid >> 3);   // grid 2048 % 8 == 0 -> bijective
    int bm = swz >> 4;    // 0..127
    int bn = swz & 15;    // 0..15

    int t = threadIdx.x;
    int l = t & 63;
    int wid = t >> 6;
    int wr = wid >> 2;    // 0..1
    int wc = wid & 3;     // 0..3
    int lr = l & 15;
    int lg = l >> 4;

    int swzc  = (lg ^ ((lr >> 1) & 3)) * 16;  // swizzled k-chunk byte offset
    int rowA0 = wr * 64 + lr;                 // + mq*16
    int rowB0 = wc * 64 + lr;                 // + nq*16

    const signed char* Abase = A + (size_t)bm * NKT * 8192;
    const signed char* Bbase = B + (size_t)bn * NKT * 16384;

    auto stage = [&](int slot, int kt) {
        const signed char* as = Abase + (size_t)kt * 8192;
        const signed char* bs = Bbase + (size_t)kt * 16384;
        signed char* da = &lds[slot * 24576];
        signed char* db = da + 8192;
        __builtin_amdgcn_global_load_lds(
            (const __attribute__((address_space(1))) unsigned int*)(as + (size_t)t * 16),
            (__attribute__((address_space(3))) unsigned int*)(da + (size_t)t * 16), 16, 0, 0);
        __builtin_amdgcn_global_load_lds(
            (const __attribute__((address_space(1))) unsigned int*)(bs + (size_t)t * 16),
            (__attribute__((address_space(3))) unsigned int*)(db + (size_t)t * 16), 16, 0, 0);
        __builtin_amdgcn_global_load_lds(
            (const __attribute__((address_space(1))) unsigned int*)(bs + 8192 + (size_t)t * 16),
            (__attribute__((address_space(3))) unsigned int*)(db + 8192 + (size_t)t * 16), 16, 0, 0);
    };

    i32x4 acc[4][4];
#pragma unroll
    for (int m = 0; m < 4; ++m)
#pragma unroll
        for (int n = 0; n < 4; ++n) acc[m][n] = (i32x4)(0);

    // Prologue: tiles 0 and 1 in flight; wait tile0 (leave tile1's 3 loads).
    stage(0, 0);
    stage(1, 1);
    asm volatile("s_waitcnt vmcnt(3)" ::: "memory");
    __builtin_amdgcn_s_barrier();
    asm volatile("" ::: "memory");

    int rs = 0;
    for (int kt = 0; kt < NKT; ++kt) {
        int wslot = rs + 2; if (wslot >= 3) wslot -= 3;
        if (kt + 2 < NKT) stage(wslot, kt + 2);   // uniform guard

        const signed char* Ap = &lds[rs * 24576];
        const signed char* Bp = Ap + 8192;
        i32x4 a[4], b[4];
#pragma unroll
        for (int mq = 0; mq < 4; ++mq)
            a[mq] = *reinterpret_cast<const i32x4*>(&Ap[(rowA0 + mq * 16) * 64 + swzc]);
#pragma unroll
        for (int nq = 0; nq < 4; ++nq)
            b[nq] = *reinterpret_cast<const i32x4*>(&Bp[(rowB0 + nq * 16) * 64 + swzc]);

#pragma unroll
        for (int mq = 0; mq < 4; ++mq)
#pragma unroll
            for (int nq = 0; nq < 4; ++nq)
                acc[mq][nq] = __builtin_amdgcn_mfma_i32_16x16x64_i8(a[mq], b[nq],
                                                                    acc[mq][nq], 0, 0, 0);

        if (kt < NKT - 2) {
            asm volatile("s_waitcnt vmcnt(3)" ::: "memory");   // tile kt+1 landed
        } else if (kt == NKT - 2) {
            asm volatile("s_waitcnt vmcnt(0)" ::: "memory");   // drain for last tile
        }
        __builtin_amdgcn_s_barrier();
        asm volatile("" ::: "memory");
        rs = (rs == 2) ? 0 : rs + 1;
    }

    // Epilogue: C/D layout col = lane&15, row = (lane>>4)*4 + reg (shape-determined)
    float scl[4][4];
#pragma unroll
    for (int mq = 0; mq < 4; ++mq)
#pragma unroll
        for (int j = 0; j < 4; ++j)
            scl[mq][j] = scales[bm * 128 + wr * 64 + mq * 16 + lg * 4 + j];

#pragma unroll
    for (int nq = 0; nq < 4; ++nq) {
        int col = bn * 256 + wc * 64 + nq * 16 + lr;
        float bv = bias[col];
#pragma unroll
        for (int mq = 0; mq < 4; ++mq)
#pragma unroll
            for (int j = 0; j < 4; ++j) {
                int row = bm * 128 + wr * 64 + mq * 16 + lg * 4 + j;
                C[(size_t)row * N_DIM + col] = (float)acc[mq][nq][j] * scl[mq][j] + bv;
            }
    }
}

// ---------------------------------------------------------------------------
// Fallback 128^2 bf16 GEMM (r2-verified), used only if ws is too small.
// ---------------------------------------------------------------------------
__global__ __launch_bounds__(256) void gemm_fb_kernel(const float* __restrict__ Af,
                                                      const float* __restrict__ Wf,
                                                      const float* __restrict__ bias,
                                                      float* __restrict__ C) {
    __shared__ unsigned short As[128 * 64];
    __shared__ unsigned short Bs[128 * 64];

    int bid = blockIdx.x;
    int swz = (bid & 7) * (4096 / 8) + (bid >> 3);
    int nt = swz & 31;
    int mt = swz >> 5;
    int m0 = mt * 128;
    int n0 = nt * 128;

    int t = threadIdx.x;
    int l = t & 63;
    int wid = t >> 6;
    int wr = wid >> 1;
    int wc = wid & 1;
    int lr = l & 15;
    int lg = l >> 4;

    f32x4 acc[4][4];
#pragma unroll
    for (int m = 0; m < 4; ++m)
#pragma unroll
        for (int n = 0; n < 4; ++n) acc[m][n] = (f32x4)(0.0f);

    for (int kt = 0; kt < 64; ++kt) {
#pragma unroll
        for (int i = 0; i < 4; ++i) {
            int off = (i * 256 + t) * 8;
            int row = off >> 6;
            int col = off & 63;
            const float4* pa =
                reinterpret_cast<const float4*>(&Af[(size_t)(m0 + row) * K_DIM + kt * 64 + col]);
            float4 a = pa[0], b = pa[1];
            bf16x8 rg;
            rg[0] = (short)f2bf(a.x); rg[1] = (short)f2bf(a.y);
            rg[2] = (short)f2bf(a.z); rg[3] = (short)f2bf(a.w);
            rg[4] = (short)f2bf(b.x); rg[5] = (short)f2bf(b.y);
            rg[6] = (short)f2bf(b.z); rg[7] = (short)f2bf(b.w);
            *reinterpret_cast<bf16x8*>(&As[off]) = rg;
        }
#pragma unroll
        for (int i = 0; i < 4; ++i) {
            int off = (i * 256 + t) * 8;
            int k = off >> 7;
            int n = off & 127;
            const float4* pw =
                reinterpret_cast<const float4*>(&Wf[(size_t)(kt * 64 + k) * N_DIM + n0 + n]);
            float4 a = pw[0], b = pw[1];
            float v[8] = {a.x, a.y, a.z, a.w, b.x, b.y, b.z, b.w};
#pragma unroll
            for (int j = 0; j < 8; ++j) Bs[(n + j) * 64 + k] = f2bf(v[j]);
        }
        __syncthreads();

#pragma unroll
        for (int ks = 0; ks < 2; ++ks) {
            bf16x8 af[4], bfr[4];
            int c = (ks << 2) | lg;
#pragma unroll
            for (int m = 0; m < 4; ++m)
                af[m] = *reinterpret_cast<const bf16x8*>(&As[(wr * 64 + m * 16 + lr) * 64 + c * 8]);
#pragma unroll
            for (int n = 0; n < 4; ++n)
                bfr[n] = *reinterpret_cast<const bf16x8*>(&Bs[(wc * 64 + n * 16 + lr) * 64 + c * 8]);
#pragma unroll
            for (int m = 0; m < 4; ++m)
#pragma unroll
                for (int n = 0; n < 4; ++n)
                    acc[m][n] = __builtin_amdgcn_mfma_f32_16x16x32_bf16(af[m], bfr[n],
                                                                        acc[m][n], 0, 0, 0);
        }
        __syncthreads();
    }

#pragma unroll
    for (int n = 0; n < 4; ++n) {
        int col = n0 + wc * 64 + n * 16 + lr;
        float bv = bias[col];
#pragma unroll
        for (int m = 0; m < 4; ++m)
#pragma unroll
            for (int j = 0; j < 4; ++j) {
                int row = m0 + wr * 64 + m * 16 + lg * 4 + j;
                C[(size_t)row * N_DIM + col] = acc[m][n][j] + bv;
            }
    }
}

// ---------------------------------------------------------------------------
extern "C" void kernel_launch(void* const* d_in, const int* in_sizes, int n_in,
                              void* d_out, int out_size, void* d_ws, size_t ws_size,
                              hipStream_t stream) {
    const float* x    = (const float*)d_in[0];
    const float* w    = (const float*)d_in[1];
    const float* bias = (const float*)d_in[2];
    float* out = (float*)d_out;

    const size_t needA = (size_t)M_DIM * K_DIM;              // 64 MB (i8)
    const size_t needB = (size_t)N_DIM * K_DIM;              // 16 MB (i8)
    const size_t needS = (size_t)M_DIM * sizeof(float);      // 64 KB

    if (ws_size >= needA + needB + needS) {
        signed char* xq = (signed char*)d_ws;
        signed char* wt = (signed char*)d_ws + needA;
        float* scales   = (float*)((char*)d_ws + needA + needB);

        quant_x_kernel<<<M_DIM, 256, 0, stream>>>(x, xq, scales);
        cvt_wt_i8_kernel<<<dim3(K_DIM / 64, N_DIM / 64), 256, 0, stream>>>(w, wt);
        gemm_i8_kernel<<<(M_DIM / 128) * (N_DIM / 256), 512, 0, stream>>>(xq, wt, bias, scales, out);
    } else {
        gemm_fb_kernel<<<(M_DIM / 128) * (N_DIM / 128), 256, 0, stream>>>(x, w, bias, out);
    }
}